// Round 1
// baseline (927.948 us; speedup 1.0000x reference)
//
#include <hip/hip_runtime.h>
#include <stdint.h>

// Problem constants (fixed by the reference)
#define B_N 8192
#define M_N 32768
#define D_N 256
#define MSPLIT 8
#define MCHUNK (M_N / MSPLIT)   // 4096 candidates per block
#define BN 64                   // candidates per LDS tile
#define TILE_BYTES (BN * 512)   // 32 KB (BN rows x 256 bf16)
#define NTILES (MCHUNK / BN)    // 64

typedef __bf16 bf16x8 __attribute__((ext_vector_type(8)));
typedef float  f32x16 __attribute__((ext_vector_type(16)));

__device__ inline float wred_sum(float v) {
#pragma unroll
  for (int off = 32; off; off >>= 1) v += __shfl_xor(v, off, 64);
  return v;
}

__device__ inline uint16_t f2bf(float f) {
  uint32_t u = __builtin_bit_cast(uint32_t, f);
  u += 0x7fffu + ((u >> 16) & 1u);
  return (uint16_t)(u >> 16);
}

// ---------------------------------------------------------------------------
// Kernel 1: normalize memory rows -> bf16, stored XOR-swizzled for LDS reads.
// Logical row c, byte off -> physical byte c*512 + (off ^ ((c&15)<<4)).
// One wave per row.
__global__ __launch_bounds__(256) void prep_mem(const float* __restrict__ mem,
                                                uint16_t* __restrict__ nm) {
  const int w = threadIdx.x >> 6, l = threadIdx.x & 63;
  const int c = blockIdx.x * 4 + w;
  const float4 v = reinterpret_cast<const float4*>(mem + (size_t)c * D_N)[l];
  float ss = v.x * v.x + v.y * v.y + v.z * v.z + v.w * v.w;
  ss = wred_sum(ss);
  const float n = sqrtf(ss);
  const float s = 1.0f / fmaxf(n, 1e-12f);
  const uint32_t lo = (uint32_t)f2bf(v.x * s) | ((uint32_t)f2bf(v.y * s) << 16);
  const uint32_t hi = (uint32_t)f2bf(v.z * s) | ((uint32_t)f2bf(v.w * s) << 16);
  const uint32_t off = ((uint32_t)(8 * l)) ^ (((uint32_t)(c & 15)) << 4);
  *reinterpret_cast<uint2*>((char*)nm + (size_t)c * 512 + off) = make_uint2(lo, hi);
}

// ---------------------------------------------------------------------------
// Kernel 2: normalize query rows -> bf16 in MFMA-B-fragment-friendly tiling:
// qt[qg][kc][lane][8 bf16] where lane = (b&31) + 32*((k>>3)&1), k = kc*16 + ...
// Also stores qnorm[b] = ||q_b||.
__global__ __launch_bounds__(256) void prep_q(const float* __restrict__ q,
                                              uint16_t* __restrict__ qt,
                                              float* __restrict__ qnorm) {
  const int w = threadIdx.x >> 6, l = threadIdx.x & 63;
  const int b = blockIdx.x * 4 + w;
  const float4 v = reinterpret_cast<const float4*>(q + (size_t)b * D_N)[l];
  float ss = v.x * v.x + v.y * v.y + v.z * v.z + v.w * v.w;
  ss = wred_sum(ss);
  const float n = sqrtf(ss);
  if (l == 0) qnorm[b] = n;
  const float s = 1.0f / fmaxf(n, 1e-12f);
  const uint32_t lo = (uint32_t)f2bf(v.x * s) | ((uint32_t)f2bf(v.y * s) << 16);
  const uint32_t hi = (uint32_t)f2bf(v.z * s) | ((uint32_t)f2bf(v.w * s) << 16);
  const int qg = b >> 5;
  const int kc = l >> 2;                       // (4l)>>4
  const int lanep = (b & 31) + 32 * ((l >> 1) & 1);
  const size_t byte = (size_t)qg * 16384 + (size_t)kc * 1024 + (size_t)lanep * 16 + 8 * (l & 1);
  *reinterpret_cast<uint2*>((char*)qt + byte) = make_uint2(lo, hi);
}

// ---------------------------------------------------------------------------
// Kernel 3: fused bf16-MFMA similarity + per-lane streaming top-8.
// Block = 256 thr = 4 waves; wave owns 32 queries (B-frags in regs).
// Grid = 64 query-chunks x MSPLIT. Writes 16 partial top-8 sets per query.
__global__ __launch_bounds__(256, 2) void topk_gemm(
    const uint16_t* __restrict__ nm, const uint16_t* __restrict__ qt,
    float* __restrict__ pv, int* __restrict__ pi) {
  __shared__ uint4 ldsbuf4[2 * TILE_BYTES / 16];
  uint8_t* lds = (uint8_t*)ldsbuf4;

  const int tid = threadIdx.x;
  const int w = tid >> 6;
  const int l = tid & 63;
  const int ln = l & 31;
  const int hi = l >> 5;
  const int qc = blockIdx.x >> 3;   // / MSPLIT
  const int ms = blockIdx.x & 7;

  // Persistent Q fragments: 16 K-chunks x 8 bf16 (64 VGPRs)
  bf16x8 qf[16];
  {
    const char* qbase = (const char*)qt + ((size_t)(qc * 4 + w) << 14) + ((size_t)l << 4);
#pragma unroll
    for (int kc = 0; kc < 16; ++kc)
      qf[kc] = *reinterpret_cast<const bf16x8*>(qbase + kc * 1024);
  }

  // per-lane top-8 state (named scalars: no dynamic indexing -> no scratch)
  float v0, v1, v2, v3, v4, v5, v6, v7;
  int i0, i1, i2, i3, i4, i5, i6, i7;
  v0 = v1 = v2 = v3 = v4 = v5 = v6 = v7 = -__builtin_inff();
  i0 = i1 = i2 = i3 = i4 = i5 = i6 = i7 = 0;
  float thr = -__builtin_inff();

  const int mstart = ms * MCHUNK;
  const char* gsrc = (const char*)nm + (size_t)mstart * 512;

  auto stage = [&](int buf, int t) {
    uint8_t* dst = lds + buf * TILE_BYTES;
    const char* src = gsrc + (size_t)t * TILE_BYTES;
#pragma unroll
    for (int r = 0; r < 8; ++r) {
      const int o = tid * 16 + r * 4096;
      __builtin_amdgcn_global_load_lds(
          (const __attribute__((address_space(1))) uint32_t*)(src + o),
          (__attribute__((address_space(3))) uint32_t*)(dst + o), 16, 0, 0);
    }
  };

  auto scan = [&](const f32x16& a, int cb) {
#pragma unroll
    for (int r = 0; r < 16; ++r) {
      const float v = a[r];
      if (v < 0.9999f && v > thr) {
        const int cand = cb + (r & 3) + 8 * (r >> 2) + 4 * hi;
        float m = v0; int s = 0;
        if (v1 < m) { m = v1; s = 1; }
        if (v2 < m) { m = v2; s = 2; }
        if (v3 < m) { m = v3; s = 3; }
        if (v4 < m) { m = v4; s = 4; }
        if (v5 < m) { m = v5; s = 5; }
        if (v6 < m) { m = v6; s = 6; }
        if (v7 < m) { m = v7; s = 7; }
        if      (s == 0) { v0 = v; i0 = cand; }
        else if (s == 1) { v1 = v; i1 = cand; }
        else if (s == 2) { v2 = v; i2 = cand; }
        else if (s == 3) { v3 = v; i3 = cand; }
        else if (s == 4) { v4 = v; i4 = cand; }
        else if (s == 5) { v5 = v; i5 = cand; }
        else if (s == 6) { v6 = v; i6 = cand; }
        else             { v7 = v; i7 = cand; }
        thr = fminf(fminf(fminf(v0, v1), fminf(v2, v3)),
                    fminf(fminf(v4, v5), fminf(v6, v7)));
      }
    }
  };

  const int swz = (ln & 15) << 4;
  const int rowa = ln * 512;
  const int rowb = rowa + 32 * 512;
  const int koff0 = hi * 16;

  stage(0, 0);
  __syncthreads();
  for (int t = 0; t < NTILES; ++t) {
    if (t + 1 < NTILES) stage((t + 1) & 1, t + 1);
    const uint8_t* buf = lds + (t & 1) * TILE_BYTES;
    f32x16 acc0 = {};
    f32x16 acc1 = {};
#pragma unroll
    for (int kc = 0; kc < 16; ++kc) {
      const int off = (kc * 32 + koff0) ^ swz;
      const bf16x8 a0 = *reinterpret_cast<const bf16x8*>(buf + rowa + off);
      const bf16x8 a1 = *reinterpret_cast<const bf16x8*>(buf + rowb + off);
      acc0 = __builtin_amdgcn_mfma_f32_32x32x16_bf16(a0, qf[kc], acc0, 0, 0, 0);
      acc1 = __builtin_amdgcn_mfma_f32_32x32x16_bf16(a1, qf[kc], acc1, 0, 0, 0);
    }
    const int cb = mstart + t * BN;
    scan(acc0, cb);
    scan(acc1, cb + 32);
    __syncthreads();
  }

  const int q = qc * 128 + w * 32 + ln;
  const int slot = ms * 2 + hi;
  float* pvq = pv + ((size_t)q << 7) + slot * 8;
  int*   piq = pi + ((size_t)q << 7) + slot * 8;
  pvq[0] = v0; pvq[1] = v1; pvq[2] = v2; pvq[3] = v3;
  pvq[4] = v4; pvq[5] = v5; pvq[6] = v6; pvq[7] = v7;
  piq[0] = i0; piq[1] = i1; piq[2] = i2; piq[3] = i3;
  piq[4] = i4; piq[5] = i5; piq[6] = i6; piq[7] = i7;
}

// ---------------------------------------------------------------------------
// Kernel 4: merge 128 partial candidates -> approx top-16 -> exact fp32
// rescore -> exact top-8 -> softmax -> weighted gather -> renorm to ||q||.
// One wave per query.
__global__ __launch_bounds__(256) void finalize(
    const float* __restrict__ query, const float* __restrict__ mem,
    const float* __restrict__ pv, const int* __restrict__ pi,
    const float* __restrict__ qnorm, float* __restrict__ out) {
  const int w = threadIdx.x >> 6, l = threadIdx.x & 63;
  const int q = blockIdx.x * 4 + w;
  const float* pvq = pv + ((size_t)q << 7);
  const int*   piq = pi + ((size_t)q << 7);
  float va = pvq[l], vb = pvq[64 + l];
  int   ia = piq[l], ib = piq[64 + l];

  // 16 argmax rounds over the 128-candidate pool (2 per lane)
  int wi[16];
#pragma unroll
  for (int j = 0; j < 16; ++j) {
    const bool pa = (va >= vb);
    float best = pa ? va : vb;
    int bl = l;
#pragma unroll
    for (int off = 32; off; off >>= 1) {
      const float ov = __shfl_xor(best, off, 64);
      const int   obl = __shfl_xor(bl, off, 64);
      if (ov > best || (ov == best && obl < bl)) { best = ov; bl = obl; }
    }
    const int myidx = pa ? ia : ib;
    wi[j] = __shfl(myidx, bl, 64);
    if (l == bl) { if (pa) va = -__builtin_inff(); else vb = -__builtin_inff(); }
  }

  // exact fp32 rescore of the 16 survivors
  const float4 q4 = reinterpret_cast<const float4*>(query + ((size_t)q << 8))[l];
  const float qn = qnorm[q];
  const float qni = 1.0f / fmaxf(qn, 1e-12f);
  float sims[16];
#pragma unroll
  for (int j = 0; j < 16; ++j) {
    const float4 m4 = reinterpret_cast<const float4*>(mem + ((size_t)wi[j] << 8))[l];
    float d  = q4.x * m4.x + q4.y * m4.y + q4.z * m4.z + q4.w * m4.w;
    float s2 = m4.x * m4.x + m4.y * m4.y + m4.z * m4.z + m4.w * m4.w;
    d = wred_sum(d);
    s2 = wred_sum(s2);
    float sim = d * qni / fmaxf(sqrtf(s2), 1e-12f);
    if (!(sim < 0.9999f)) sim = -__builtin_inff();   // self-match mask (exact)
    sims[j] = sim;
  }

  // rank-based exact top-8 of 16 (branchless, static indexing)
  int rank[16];
#pragma unroll
  for (int j = 0; j < 16; ++j) {
    int rk = 0;
#pragma unroll
    for (int k2 = 0; k2 < 16; ++k2) {
      if (k2 == j) continue;
      rk += (sims[k2] > sims[j] || (sims[k2] == sims[j] && k2 < j)) ? 1 : 0;
    }
    rank[j] = rk;
  }
  float mx = -__builtin_inff();
#pragma unroll
  for (int j = 0; j < 16; ++j)
    if (rank[j] < 8) mx = fmaxf(mx, sims[j]);
  float e[16];
  float se = 0.0f;
#pragma unroll
  for (int j = 0; j < 16; ++j) {
    e[j] = (rank[j] < 8) ? expf(sims[j] - mx) : 0.0f;
    se += e[j];
  }
  const float inv = 1.0f / se;

  // weighted gather of the 8 selected original memory rows
  float rx = 0.f, ry = 0.f, rz = 0.f, rw = 0.f;
#pragma unroll
  for (int j = 0; j < 16; ++j) {
    const float wj = e[j] * inv;
    if (wj > 0.0f) {  // wave-uniform
      const float4 m4 = reinterpret_cast<const float4*>(mem + ((size_t)wi[j] << 8))[l];
      rx += wj * m4.x; ry += wj * m4.y; rz += wj * m4.z; rw += wj * m4.w;
    }
  }
  float ss = rx * rx + ry * ry + rz * rz + rw * rw;
  ss = wred_sum(ss);
  const float sc = qn / fmaxf(sqrtf(ss), 1e-12f);
  float4 o4;
  o4.x = rx * sc; o4.y = ry * sc; o4.z = rz * sc; o4.w = rw * sc;
  reinterpret_cast<float4*>(out + ((size_t)q << 8))[l] = o4;
}

// ---------------------------------------------------------------------------
extern "C" void kernel_launch(void* const* d_in, const int* in_sizes, int n_in,
                              void* d_out, int out_size, void* d_ws, size_t ws_size,
                              hipStream_t stream) {
  const float* query = (const float*)d_in[0];
  const float* mem   = (const float*)d_in[1];
  (void)in_sizes; (void)n_in; (void)out_size; (void)ws_size;

  char* ws = (char*)d_ws;
  uint16_t* nm    = (uint16_t*)(ws);                      // 16 MB swizzled bf16 memory
  uint16_t* qt    = (uint16_t*)(ws + (16u << 20));        //  4 MB tiled bf16 queries
  float*    qnorm = (float*)   (ws + (20u << 20));        // 32 KB
  float*    pv    = (float*)   (ws + (21u << 20));        //  4 MB partial vals
  int*      pi    = (int*)     (ws + (25u << 20));        //  4 MB partial idx

  prep_mem<<<M_N / 4, 256, 0, stream>>>(mem, nm);
  prep_q<<<B_N / 4, 256, 0, stream>>>(query, qt, qnorm);
  topk_gemm<<<(B_N / 128) * MSPLIT, 256, 0, stream>>>(nm, qt, pv, pi);
  finalize<<<B_N / 4, 256, 0, stream>>>(query, mem, pv, pi, qnorm, (float*)d_out);
}